// Round 13
// baseline (660.872 us; speedup 1.0000x reference)
//
#include <hip/hip_runtime.h>
#include <hip/hip_bf16.h>
#include <stdint.h>

typedef __attribute__((ext_vector_type(8))) short short8;
typedef __attribute__((ext_vector_type(4))) float f32x4;

#define AS1 __attribute__((address_space(1)))
#define AS3 __attribute__((address_space(3)))

// RNE float->bf16 (inputs are finite; no NaN handling needed)
static __device__ __forceinline__ unsigned short f2bf(float f) {
    unsigned int u = __float_as_uint(f);
    u += 0x7FFFu + ((u >> 16) & 1u);
    return (unsigned short)(u >> 16);
}

__global__ void init_amax(unsigned int* amax) {
    if (threadIdx.x < 2) amax[threadIdx.x] = 0u;
}

__global__ void absmax_kernel(const float4* __restrict__ w, size_t n4,
                              unsigned int* __restrict__ out) {
    float m = 0.0f;
    size_t i = (size_t)blockIdx.x * blockDim.x + threadIdx.x;
    size_t stride = (size_t)gridDim.x * blockDim.x;
    for (; i < n4; i += stride) {
        float4 v = w[i];
        m = fmaxf(m, fmaxf(fmaxf(fabsf(v.x), fabsf(v.y)),
                           fmaxf(fabsf(v.z), fabsf(v.w))));
    }
    #pragma unroll
    for (int off = 32; off > 0; off >>= 1)
        m = fmaxf(m, __shfl_down(m, off, 64));
    __shared__ float sm[4];
    int lane = threadIdx.x & 63, wid = threadIdx.x >> 6;
    if (lane == 0) sm[wid] = m;
    __syncthreads();
    if (threadIdx.x == 0) {
        float bm = fmaxf(fmaxf(sm[0], sm[1]), fmaxf(sm[2], sm[3]));
        atomicMax(out, __float_as_uint(bm));  // floats >=0: uint bit-compare monotone
    }
}

// FP4 E2M1 quantize to exact bf16 grid value (scale kept separate).
// idx = sum(a > mids[j]) matches np.searchsorted(mids, a, side='left').
static __device__ __forceinline__ unsigned short quant_one(float wv, float scale) {
    float a = fabsf(wv) / scale;
    int idx = (a > 0.25f) + (a > 0.75f) + (a > 1.25f) + (a > 1.75f)
            + (a > 2.5f)  + (a > 3.5f)  + (a > 5.0f);
    const unsigned long long lo = 0x3FC03F803F000000ull;  // bf16 bits {0,.5,1,1.5}
    const unsigned long long hi = 0x40C0408040404000ull;  // bf16 bits {2,3,4,6}
    unsigned long long tab = (idx < 4) ? lo : hi;
    unsigned short mag = (unsigned short)(tab >> ((idx & 3) * 16));
    unsigned short sgn = (unsigned short)((__float_as_uint(wv) >> 16) & 0x8000u);
    return (unsigned short)(mag | sgn);
}

__global__ void quant_kernel(const float4* __restrict__ w, size_t n4,
                             const unsigned int* __restrict__ amax,
                             ushort4* __restrict__ q) {
    const float scale = __uint_as_float(*amax) / 6.0f;
    size_t i = (size_t)blockIdx.x * blockDim.x + threadIdx.x;
    size_t stride = (size_t)gridDim.x * blockDim.x;
    for (; i < n4; i += stride) {
        float4 v = w[i];
        ushort4 o;
        o.x = quant_one(v.x, scale);
        o.y = quant_one(v.y, scale);
        o.z = quant_one(v.z, scale);
        o.w = quant_one(v.w, scale);
        q[i] = o;
    }
}

__global__ void cast_bf16_kernel(const float4* __restrict__ x, size_t n4,
                                 ushort4* __restrict__ o) {
    size_t i = (size_t)blockIdx.x * blockDim.x + threadIdx.x;
    size_t stride = (size_t)gridDim.x * blockDim.x;
    for (; i < n4; i += stride) {
        float4 v = x[i];
        ushort4 r;
        r.x = f2bf(v.x); r.y = f2bf(v.y); r.z = f2bf(v.z); r.w = f2bf(v.w);
        o[i] = r;
    }
}

// ==== 256x256 GEMM, BK=64, 4-cluster software pipeline, 1 barrier/tile ====
// C[M][N] = A[M][K] (bf16) * B[N][K]^T (bf16), f32 acc.
// 512 thr = 8 waves (2M x 4N), wave tile 128x64, acc[8][4] f32x4.
// LDS 128KiB = 2 bufs x 64KB (tile parity); per buf: A0@0 A1@16K B0@32K B1@48K.
// Subtile = 16 rows x 32 k (1024B); byte = swz(rin*64+kin*2), swz(x)=x^(((x>>9)&1)<<5).
// global_load_lds dest LINEAR; global source carries inverse swizzle (R6/R9-verified).
//
// K-tile = 4 MFMA clusters of 16: C00(aP,bE) C10(aQ,bE) C01(aP',bO) C11(aQ',bO).
// The NEXT chunk's 4 ds_reads are issued in slots BETWEEN the MFMAs of the
// CURRENT cluster, so they retire during MFMA execution (m201/m196 interleave
// mechanism). Counted lgkm waits all target reads issued >=1 cluster earlier.
// DS ledger/tile: enter 8 (b0,aP0 from prev C11) -> LGKM(0)=0; C00 issues
// aQ0+bO -> 8, LGKM(4) retires aQ0; C10 issues aP1 -> 8, LGKM(0); C01 issues
// aQ1 -> 4, LGKM(0); sync; C11 issues next-tile b0,aP0 -> 8.
// Sync (1 barrier): LGKM(0); vmcnt(0) [tile t+1's stage, issued a FULL tile
// (~2700 cyc >= 900 HBM) earlier -> free]; BAR [all waves: buf free + t+1
// visible]; stage t+2 (8 GLL) into the freed buf.
// LAYA=1: A is H'-blocked (GEMM1's epilogue layout): f(row,k) = (row>>4)*262144
// + (k>>4)*512 + (row&3)*128 + ((row>>2)&3)*32 + (k&15)*2.

#define GLL(gp, dst)                                                    \
    __builtin_amdgcn_global_load_lds((const AS1 unsigned int*)(gp),     \
        (AS3 unsigned int*)(dst), 16, 0, 0)

// byte advance for a k-offset of e ELEMENTS
#define KAB(e) ((size_t)(e) * (LAYA ? 32 : 2))
#define KBB(e) ((size_t)(e) * 2)

// stage one full K-tile (A 32KB + B 32KB) at byte offsets kA/kB into buf
#define STAGE_T(kA, kB, bufw)                                           \
    { GLL(pA0 + (kA) + goffA0, lds + (bufw) + tid * 16);                \
      GLL(pA0 + (kA) + goffA1, lds + (bufw) + 8192 + tid * 16);         \
      GLL(pA1 + (kA) + goffA0, lds + (bufw) + 16384 + tid * 16);        \
      GLL(pA1 + (kA) + goffA1, lds + (bufw) + 24576 + tid * 16);        \
      GLL(pB0 + (kB) + goffB0, lds + (bufw) + 32768 + tid * 16);        \
      GLL(pB0 + (kB) + goffB1, lds + (bufw) + 40960 + tid * 16);        \
      GLL(pB1 + (kB) + goffB0, lds + (bufw) + 49152 + tid * 16);        \
      GLL(pB1 + (kB) + goffB1, lds + (bufw) + 57344 + tid * 16); }

// 4 ds_read_b128: dst[i] = subtile (s0 + 2*i)
#define LD4P(dst, base, s0)                                             \
    { dst[0] = *(const short8*)((base) + (s0) * 1024);                  \
      dst[1] = *(const short8*)((base) + ((s0) + 2) * 1024);            \
      dst[2] = *(const short8*)((base) + ((s0) + 4) * 1024);            \
      dst[3] = *(const short8*)((base) + ((s0) + 6) * 1024); }

#define NOP9 ((void)0)

#define MQ1(AH, I, J, ARR, BRR)                                         \
    acc[(AH) * 4 + (I)][J] = __builtin_amdgcn_mfma_f32_16x16x32_bf16(   \
        ARR[I], BRR[J], acc[(AH) * 4 + (I)][J], 0, 0, 0)

#define BAR()  __builtin_amdgcn_s_barrier()
#define PRIO(x) __builtin_amdgcn_s_setprio(x)
#define SCHB() __builtin_amdgcn_sched_barrier(0)
#define LGKM(n) do { SCHB(); asm volatile("s_waitcnt lgkmcnt(" #n ")"); SCHB(); } while (0)

// 16-MFMA cluster with read-issue slots after MFMA #2 and #6
#define CLUST(AH, ARR, BRR, S1, S2)                                     \
    { MQ1(AH,0,0,ARR,BRR); MQ1(AH,1,0,ARR,BRR);                         \
      SCHB(); S1; SCHB();                                               \
      MQ1(AH,2,0,ARR,BRR); MQ1(AH,3,0,ARR,BRR);                         \
      MQ1(AH,0,1,ARR,BRR); MQ1(AH,1,1,ARR,BRR);                         \
      SCHB(); S2; SCHB();                                               \
      MQ1(AH,2,1,ARR,BRR); MQ1(AH,3,1,ARR,BRR);                         \
      MQ1(AH,0,2,ARR,BRR); MQ1(AH,1,2,ARR,BRR);                         \
      MQ1(AH,2,2,ARR,BRR); MQ1(AH,3,2,ARR,BRR);                         \
      MQ1(AH,0,3,ARR,BRR); MQ1(AH,1,3,ARR,BRR);                         \
      MQ1(AH,2,3,ARR,BRR); MQ1(AH,3,3,ARR,BRR); }

// One K-tile. STG_STMT: stage of tile t+2 (or NOP9). DO_VM: vmcnt(0) at sync.
// SL1/SL2: C11 slots = next tile's b0/aP0 ds_reads (or NOP9 at the tail).
#define KTILE(ldsAc, ldsBc, STG_STMT, DO_VM, SL1, SL2)                        \
    do {                                                                      \
        LGKM(0);   /* b0,aP0 retired (issued during prev C11 / prologue) */   \
        PRIO(1); CLUST(0, aP, bE, LD4P(aQ, ldsAc, 8), LD4P(bO, ldsBc, 1));    \
        PRIO(0);                                                              \
        LGKM(4);   /* aQ0 retired; bO in flight */                            \
        PRIO(1); CLUST(1, aQ, bE, LD4P(aP, ldsAc, 1), NOP9); PRIO(0);         \
        LGKM(0);   /* bO + aP1 retired */                                     \
        PRIO(1); CLUST(0, aP, bO, LD4P(aQ, ldsAc, 9), NOP9); PRIO(0);         \
        LGKM(0);   /* aQ1 retired -> own buf reads done */                    \
        if (DO_VM) { asm volatile("s_waitcnt vmcnt(0)"); }                    \
        BAR();     /* all waves: buf free + next tile's stage visible */      \
        STG_STMT;                                                             \
        SCHB();                                                               \
        PRIO(1); CLUST(1, aQ, bO, SL1, SL2); PRIO(0);                         \
    } while (0)

template <int RELU_BF16, int LAYA>
__global__ __launch_bounds__(512, 2)
void gemm8(const char* __restrict__ A,          // LAYA=0: row-major bf16; 1: H'-blocked
           const unsigned short* __restrict__ B,
           const float* __restrict__ bias,
           const unsigned int* __restrict__ amax,
           float* __restrict__ outF,            // RELU_BF16=0 dest (row-major f32)
           char* __restrict__ outH,             // RELU_BF16=1 dest (H'-blocked bf16)
           int M, int N, int K, int gx, int cw) {
    __shared__ __align__(16) char lds[131072];

    const int tid  = threadIdx.x;
    const int lane = tid & 63;
    const int wid  = tid >> 6;
    const int wm   = wid >> 2;   // 0..1: 128-row half
    const int wn   = wid & 3;    // 0..3: 64-col slice

    // 2D-chunked XCD mapping (R9-verified)
    const int nwg = gridDim.x;
    const int wg  = blockIdx.x;
    const int c   = wg & 7;
    const int idx = wg >> 3;
    const int nc  = nwg >> 3;
    const int cxc = gx / cw;
    const int ox  = (c % cxc) * cw;
    const int oy  = (c / cxc) * (nc / cw);
    const int bx  = ox + idx % cw;
    const int by  = oy + idx / cw;
    const int col0 = bx * 256;
    const int row0 = by * 256;

    // per-lane swizzled ds_read byte offset within a 1024B subtile
    int sp = ((lane & 15) << 6) + ((lane >> 4) << 4);
    sp ^= ((sp >> 9) & 1) << 5;

    const char* ldsA_E = lds + wm * 16384 + sp;
    const char* ldsB_E = lds + 32768 + (wn >> 1) * 16384 + (wn & 1) * 8192 + sp;
    const char* ldsA_O = ldsA_E + 65536;
    const char* ldsB_O = ldsB_E + 65536;

    // stage source byte-offsets: LDS linear off o = h*8192 + tid*16 holds
    // element (row,k) = unswz(o); A offset per LAYA, B row-major. (R12-verified)
    int goffA0, goffA1, goffB0, goffB1;
    {
        #pragma unroll
        for (int h = 0; h < 2; ++h) {
            int o = h * 8192 + tid * 16;
            int s = o >> 10, b = o & 1023;
            b ^= ((b >> 9) & 1) << 5;
            int row = ((s >> 1) << 4) + (b >> 6);
            int k   = ((s & 1) << 5) + ((b & 63) >> 1);
            int gB  = (row * K + k) * 2;
            int gA  = LAYA ? ((row >> 4) * 262144 + (k >> 4) * 512 +
                              (row & 3) * 128 + ((row >> 2) & 3) * 32 + (k & 15) * 2)
                           : gB;
            if (h == 0) { goffA0 = gA; goffB0 = gB; }
            else        { goffA1 = gA; goffB1 = gB; }
        }
    }
    const char* pA0 = A + (LAYA ? (size_t)row0 * 16384 : (size_t)row0 * K * 2);
    const char* pA1 = A + (LAYA ? (size_t)(row0 + 128) * 16384
                                : (size_t)(row0 + 128) * K * 2);
    const char* pB0 = (const char*)B + (size_t)col0 * K * 2;
    const char* pB1 = (const char*)B + (size_t)(col0 + 128) * K * 2;

    f32x4 acc[8][4] = {};
    short8 aP[4], aQ[4], bE[4], bO[4];

    // prologue: stage tiles 0,1; wait tile0; prefetch tile0's b0/aP0
    STAGE_T(0, 0, 0);
    STAGE_T(KAB(64), KBB(64), 65536);
    asm volatile("s_waitcnt vmcnt(8)");   // tile0's 8 landed (tile1's 8 remain)
    BAR();
    LD4P(bE, ldsB_E, 0);
    LD4P(aP, ldsA_E, 0);

    const int NT = K >> 6;
    const int NP = NT >> 1;

    for (int p = 0; p < NP - 1; ++p) {
        const size_t a2 = KAB((size_t)(p * 2 + 2) * 64);
        const size_t b2 = KBB((size_t)(p * 2 + 2) * 64);
        // tile 2p (E): stage 2p+2 -> E; prefetch 2p+1 reads from O
        KTILE(ldsA_E, ldsB_E, STAGE_T(a2, b2, 0), 1,
              LD4P(bE, ldsB_O, 0), LD4P(aP, ldsA_O, 0));
        // tile 2p+1 (O): stage 2p+3 -> O; prefetch 2p+2 reads from E
        KTILE(ldsA_O, ldsB_O, STAGE_T(a2 + KAB(64), b2 + KBB(64), 65536), 1,
              LD4P(bE, ldsB_E, 0), LD4P(aP, ldsA_E, 0));
    }
    // tail pair: tile NT-2 (E): no stage; vmcnt(0) retires NT-1's stage
    KTILE(ldsA_E, ldsB_E, NOP9, 1,
          LD4P(bE, ldsB_O, 0), LD4P(aP, ldsA_O, 0));
    // tile NT-1 (O): nothing outstanding
    KTILE(ldsA_O, ldsB_O, NOP9, 0, NOP9, NOP9);

    // acc C/D layout (verified m89/m91): col = lane&15, row = (lane>>4)*4 + r
    const float scale = __uint_as_float(*amax) / 6.0f;

    if (RELU_BF16) {
        // H'-blocked store: per (j,i,r) one 2B store, 64 lanes span 128B contiguous
        const int gbit = (lane >> 4) * 32 + (lane & 15) * 2;
        #pragma unroll
        for (int j = 0; j < 4; ++j) {
            const int col = col0 + wn * 64 + j * 16 + (lane & 15);
            const float bvv = bias[col];
            const size_t ktb = (size_t)((col0 >> 4) + wn * 4 + j) * 512;
            #pragma unroll
            for (int i = 0; i < 8; ++i) {
                const size_t rtb = (size_t)(((row0 + wm * 128) >> 4) + i) * 262144;
                #pragma unroll
                for (int r = 0; r < 4; ++r) {
                    float v = fmaxf(acc[i][j][r] * scale + bvv, 0.0f);
                    *(unsigned short*)(outH + rtb + ktb + r * 128 + gbit) = f2bf(v);
                }
            }
        }
    } else {
        // f32 out via LDS: 2 passes (wm groups); 16B-block XOR keyed on (row>>2)&3
        #pragma unroll
        for (int p2 = 0; p2 < 2; ++p2) {
            if (wm == p2) {
                #pragma unroll
                for (int j = 0; j < 4; ++j) {
                    const int colb = wn * 64 + j * 16 + (lane & 15);
                    const float bvv = bias[col0 + colb];
                    #pragma unroll
                    for (int i = 0; i < 8; ++i) {
                        #pragma unroll
                        for (int r = 0; r < 4; ++r) {
                            const int row_l = i * 16 + (lane >> 4) * 4 + r;
                            const int blk = (colb >> 2) ^ (((row_l >> 2) & 3) << 2);
                            *(float*)(lds + row_l * 1024 + blk * 16 + (colb & 3) * 4)
                                = acc[i][j][r] * scale + bvv;
                        }
                    }
                }
            }
            asm volatile("s_waitcnt lgkmcnt(0)");
            BAR();
            #pragma unroll
            for (int q = 0; q < 16; ++q) {
                const int flat  = q * 8192 + tid * 16;
                const int row_l = flat >> 10;
                const int blk0  = (flat >> 4) & 63;
                const int blk   = blk0 ^ (((row_l >> 2) & 3) << 2);
                f32x4 v = *(const f32x4*)(lds + row_l * 1024 + blk * 16);
                *(f32x4*)(outF + (size_t)(row0 + p2 * 128 + row_l) * N
                                 + col0 + blk0 * 4) = v;
            }
            BAR();
        }
    }
}

extern "C" void kernel_launch(void* const* d_in, const int* in_sizes, int n_in,
                              void* d_out, int out_size, void* d_ws, size_t ws_size,
                              hipStream_t stream) {
    const float* x  = (const float*)d_in[0];   // [8192, 2048]
    const float* W1 = (const float*)d_in[1];   // [8192, 2048]
    const float* b1 = (const float*)d_in[2];   // [8192]
    const float* W2 = (const float*)d_in[3];   // [2048, 8192]
    const float* b2 = (const float*)d_in[4];   // [2048]
    float* out = (float*)d_out;                // [8192, 2048] f32

    const int Bm = 8192, Din = 2048, Dh = 8192, Dout = 2048;
    const size_t nW1 = (size_t)Dh * Din;
    const size_t nW2 = (size_t)Dout * Dh;
    const size_t nX  = (size_t)Bm * Din;
    const size_t nH  = (size_t)Bm * Dh;

    const size_t need = 256 + 2 * (nW1 + nW2 + nX + nH);
    if (ws_size < need) return;

    uint8_t* ws = (uint8_t*)d_ws;
    unsigned int*   amax = (unsigned int*)ws;
    unsigned short* Q1 = (unsigned short*)(ws + 256);
    unsigned short* Q2 = Q1 + nW1;
    unsigned short* Xb = Q2 + nW2;
    char*           H  = (char*)(Xb + nX);     // H'-blocked bf16, nH*2 bytes

    init_amax<<<1, 64, 0, stream>>>(amax);
    absmax_kernel<<<1024, 256, 0, stream>>>((const float4*)W1, nW1 / 4, amax + 0);
    absmax_kernel<<<1024, 256, 0, stream>>>((const float4*)W2, nW2 / 4, amax + 1);
    quant_kernel<<<2048, 256, 0, stream>>>((const float4*)W1, nW1 / 4, amax + 0, (ushort4*)Q1);
    quant_kernel<<<2048, 256, 0, stream>>>((const float4*)W2, nW2 / 4, amax + 1, (ushort4*)Q2);
    cast_bf16_kernel<<<2048, 256, 0, stream>>>((const float4*)x, nX / 4, (ushort4*)Xb);

    // h = relu(scale1 * (x @ Q1^T) + b1) -> H'-blocked bf16
    gemm8<1, 0><<<dim3((Dh / 256) * (Bm / 256)), 512, 0, stream>>>(
        (const char*)Xb, Q1, b1, amax + 0, nullptr, H,
        Bm, Dh, Din, /*gx=*/Dh / 256, /*cw=*/16);
    // y = scale2 * (h @ Q2^T) + b2 -> f32 row-major
    gemm8<0, 1><<<dim3((Dout / 256) * (Bm / 256)), 512, 0, stream>>>(
        H, Q2, b2, amax + 1, out, nullptr,
        Bm, Dout, Dh, /*gx=*/Dout / 256, /*cw=*/8);
}

// Round 14
// 534.194 us; speedup vs baseline: 1.2371x; 1.2371x over previous
//
#include <hip/hip_runtime.h>
#include <hip/hip_bf16.h>
#include <stdint.h>

typedef __attribute__((ext_vector_type(8))) short short8;
typedef __attribute__((ext_vector_type(4))) float f32x4;

#define AS1 __attribute__((address_space(1)))
#define AS3 __attribute__((address_space(3)))

// RNE float->bf16 (inputs are finite; no NaN handling needed)
static __device__ __forceinline__ unsigned short f2bf(float f) {
    unsigned int u = __float_as_uint(f);
    u += 0x7FFFu + ((u >> 16) & 1u);
    return (unsigned short)(u >> 16);
}

__global__ void init_amax(unsigned int* amax) {
    if (threadIdx.x < 2) amax[threadIdx.x] = 0u;
}

__global__ void absmax_kernel(const float4* __restrict__ w, size_t n4,
                              unsigned int* __restrict__ out) {
    float m = 0.0f;
    size_t i = (size_t)blockIdx.x * blockDim.x + threadIdx.x;
    size_t stride = (size_t)gridDim.x * blockDim.x;
    for (; i < n4; i += stride) {
        float4 v = w[i];
        m = fmaxf(m, fmaxf(fmaxf(fabsf(v.x), fabsf(v.y)),
                           fmaxf(fabsf(v.z), fabsf(v.w))));
    }
    #pragma unroll
    for (int off = 32; off > 0; off >>= 1)
        m = fmaxf(m, __shfl_down(m, off, 64));
    __shared__ float sm[4];
    int lane = threadIdx.x & 63, wid = threadIdx.x >> 6;
    if (lane == 0) sm[wid] = m;
    __syncthreads();
    if (threadIdx.x == 0) {
        float bm = fmaxf(fmaxf(sm[0], sm[1]), fmaxf(sm[2], sm[3]));
        atomicMax(out, __float_as_uint(bm));  // floats >=0: uint bit-compare monotone
    }
}

// FP4 E2M1 quantize to exact bf16 grid value (scale kept separate).
// idx = sum(a > mids[j]) matches np.searchsorted(mids, a, side='left').
static __device__ __forceinline__ unsigned short quant_one(float wv, float scale) {
    float a = fabsf(wv) / scale;
    int idx = (a > 0.25f) + (a > 0.75f) + (a > 1.25f) + (a > 1.75f)
            + (a > 2.5f)  + (a > 3.5f)  + (a > 5.0f);
    const unsigned long long lo = 0x3FC03F803F000000ull;  // bf16 bits {0,.5,1,1.5}
    const unsigned long long hi = 0x40C0408040404000ull;  // bf16 bits {2,3,4,6}
    unsigned long long tab = (idx < 4) ? lo : hi;
    unsigned short mag = (unsigned short)(tab >> ((idx & 3) * 16));
    unsigned short sgn = (unsigned short)((__float_as_uint(wv) >> 16) & 0x8000u);
    return (unsigned short)(mag | sgn);
}

__global__ void quant_kernel(const float4* __restrict__ w, size_t n4,
                             const unsigned int* __restrict__ amax,
                             ushort4* __restrict__ q) {
    const float scale = __uint_as_float(*amax) / 6.0f;
    size_t i = (size_t)blockIdx.x * blockDim.x + threadIdx.x;
    size_t stride = (size_t)gridDim.x * blockDim.x;
    for (; i < n4; i += stride) {
        float4 v = w[i];
        ushort4 o;
        o.x = quant_one(v.x, scale);
        o.y = quant_one(v.y, scale);
        o.z = quant_one(v.z, scale);
        o.w = quant_one(v.w, scale);
        q[i] = o;
    }
}

__global__ void cast_bf16_kernel(const float4* __restrict__ x, size_t n4,
                                 ushort4* __restrict__ o) {
    size_t i = (size_t)blockIdx.x * blockDim.x + threadIdx.x;
    size_t stride = (size_t)gridDim.x * blockDim.x;
    for (; i < n4; i += stride) {
        float4 v = x[i];
        ushort4 r;
        r.x = f2bf(v.x); r.y = f2bf(v.y); r.z = f2bf(v.z); r.w = f2bf(v.w);
        o[i] = r;
    }
}

// ========== 256x256 GEMM, BK=64, group-pipelined (R6 core, verified) ==========
// C[M][N] = A[M][K] (bf16) * B[N][K]^T (bf16), f32 acc.
// 512 thr = 8 waves (2M x 4N), per-wave 128x64, 2 K-tiles/iter.
// LDS 128KiB, buf by tile parity; per buf: A0@0 A1@16K B0@32K B1@48K.
// Subtile = 16 rows x 32 k (1024B); byte = swz(rin*64+kin*2), swz(x)=x^(((x>>9)&1)<<5).
// global_load_lds dest LINEAR; global source carries inverse swizzle.
//
// LAYA=1: A is the H'-BLOCKED internal layout (written by GEMM1's epilogue):
//   f(row,k) = (row>>4)*262144 + (k>>4)*512 + (row&3)*128 + ((row>>2)&3)*32 + (k&15)*2
// 16B of f = 8 consecutive k of one row -> drop-in for the A staging chunks.
// GEMM1 epilogue stores H' 128B-contiguous per instr (kills the 2x write amp).
// GEMM2 (f32 out) epilogue goes via LDS -> full-row 1KB coalesced stores.
//
// FINAL STATE (R12 revert, verified best of 7 structural variants R2..R13):
// 534 us total, gemm ~262 us each (~1060 TF, 42% dense peak), conflicts 0.
// Register-capped at 8 waves/CU (acc 128 AGPR + ~100 VGPR ≈ 230/wave):
// R10 (2 blocks/CU), R11 (3-deep), R13 (hand-interleave -> spill) all worse.

#define GLL(gp, dst)                                                    \
    __builtin_amdgcn_global_load_lds((const AS1 unsigned int*)(gp),     \
        (AS3 unsigned int*)(dst), 16, 0, 0)

#define STGA(gp, ldsoff)                                        \
    do {                                                        \
        GLL((gp) + goffA0, lds + (ldsoff) + tid * 16);          \
        GLL((gp) + goffA1, lds + (ldsoff) + 8192 + tid * 16);   \
    } while (0)

#define STGB(gp, ldsoff)                                        \
    do {                                                        \
        GLL((gp) + goffB0, lds + (ldsoff) + tid * 16);          \
        GLL((gp) + goffB1, lds + (ldsoff) + 8192 + tid * 16);   \
    } while (0)

// byte advance for a k-offset of e ELEMENTS
#define KAB(e) ((size_t)(e) * (LAYA ? 32 : 2))
#define KBB(e) ((size_t)(e) * 2)

// 4 ds_read_b128: dst[i] = subtile (s0 + 2*i) of base
#define LD4(dst, base, s0)                                                    \
    do {                                                                      \
        _Pragma("unroll") for (int _i = 0; _i < 4; ++_i)                      \
            dst[_i] = *(const short8*)((base) + ((s0) + _i * 2) * 1024);      \
    } while (0)

// 16 MFMA: acc[AH*4 + i][j] += ARR[i] * BRR[j]
#define MFG(AH, ARR, BRR)                                                      \
    do {                                                                       \
        _Pragma("unroll") for (int _i = 0; _i < 4; ++_i)                       \
            _Pragma("unroll") for (int _j = 0; _j < 4; ++_j)                   \
                acc[(AH) * 4 + _i][_j] =                                       \
                    __builtin_amdgcn_mfma_f32_16x16x32_bf16(                   \
                        ARR[_i], BRR[_j], acc[(AH) * 4 + _i][_j], 0, 0, 0);    \
    } while (0)

#define BAR()  __builtin_amdgcn_s_barrier()
#define PRIO(x) __builtin_amdgcn_s_setprio(x)
#define SCHB() __builtin_amdgcn_sched_barrier(0)
#define LGKM(n) do { SCHB(); asm volatile("s_waitcnt lgkmcnt(" #n ")"); SCHB(); } while (0)

// One K-tile (R6-verified). VMODE: 2 = vmcnt(6), 1 = vmcnt(0), 0 = none.
#define KTILE(ldsB_, ldsA_, MA1, kA1, oA1, MORE, kNXT, oB0, oB1, oA0, VMODE)   \
    do {                                                                       \
        LD4(bE, ldsB_, 0);             /* B κ0: 4 reads */                     \
        LD4(aP, ldsA_, 0);             /* A h0 κ0: 4 */                        \
        LD4(aQ, ldsA_, 8);             /* A h1 κ0: 4 */                        \
        if (MA1) STGA(pA1 + KAB(kA1), oA1);                                    \
        LGKM(4);                       /* bE+aP ready, aQ in flight */         \
        PRIO(1); MFG(0, aP, bE); PRIO(0);                                      \
        LD4(bO, ldsB_, 1);             /* B κ1: 4 */                           \
        LD4(aP, ldsA_, 1);             /* A h0 κ1: 4 */                        \
        LGKM(8);                       /* aQ ready; bO,aP' in flight */        \
        PRIO(1); MFG(1, aQ, bE); PRIO(0);                                      \
        LD4(aQ, ldsA_, 9);             /* A h1 κ1: 4 */                        \
        LGKM(4);                       /* bO+aP' ready; aQ' in flight */       \
        PRIO(1); MFG(0, aP, bO); PRIO(0);                                      \
        LGKM(0);                       /* all 24 reads done -> buf free */     \
        BAR();                                                                 \
        if (MORE) { STGB(pB0 + KBB(kNXT), oB0); STGB(pB1 + KBB(kNXT), oB1);    \
                    STGA(pA0 + KAB(kNXT), oA0); }                              \
        SCHB();                                                                \
        PRIO(1); MFG(1, aQ, bO); PRIO(0);                                      \
        if (VMODE == 2) { asm volatile("s_waitcnt vmcnt(6)"); }                \
        if (VMODE == 1) { asm volatile("s_waitcnt vmcnt(0)"); }                \
        BAR();                                                                 \
    } while (0)

template <int RELU_BF16, int LAYA>
__global__ __launch_bounds__(512, 2)
void gemm8(const char* __restrict__ A,          // LAYA=0: row-major bf16; 1: H'-blocked
           const unsigned short* __restrict__ B,
           const float* __restrict__ bias,
           const unsigned int* __restrict__ amax,
           float* __restrict__ outF,            // RELU_BF16=0 dest (row-major f32)
           char* __restrict__ outH,             // RELU_BF16=1 dest (H'-blocked bf16)
           int M, int N, int K, int gx, int cw) {
    __shared__ __align__(16) char lds[131072];

    const int tid  = threadIdx.x;
    const int lane = tid & 63;
    const int wid  = tid >> 6;
    const int wm   = wid >> 2;   // 0..1: 128-row half
    const int wn   = wid & 3;    // 0..3: 64-col slice

    // 2D-chunked XCD mapping: XCD c gets a cw x (nc/cw) block-rect; bx fastest
    const int nwg = gridDim.x;
    const int wg  = blockIdx.x;
    const int c   = wg & 7;
    const int idx = wg >> 3;
    const int nc  = nwg >> 3;
    const int cxc = gx / cw;                 // chunks along x
    const int ox  = (c % cxc) * cw;
    const int oy  = (c / cxc) * (nc / cw);
    const int bx  = ox + idx % cw;
    const int by  = oy + idx / cw;
    const int col0 = bx * 256;
    const int row0 = by * 256;

    // per-lane swizzled ds_read byte offset within a 1024B subtile
    int sp = ((lane & 15) << 6) + ((lane >> 4) << 4);
    sp ^= ((sp >> 9) & 1) << 5;

    const char* ldsA_E = lds + wm * 16384 + sp;
    const char* ldsB_E = lds + 32768 + (wn >> 1) * 16384 + (wn & 1) * 8192 + sp;
    const char* ldsA_O = ldsA_E + 65536;
    const char* ldsB_O = ldsB_E + 65536;

    // stage source byte-offsets: LDS linear off o = l*8192 + tid*16 holds
    // element (row,k) = unswz(o); A offset per LAYA, B row-major.
    int goffA0, goffA1, goffB0, goffB1;
    {
        #pragma unroll
        for (int h = 0; h < 2; ++h) {
            int o = h * 8192 + tid * 16;
            int s = o >> 10, b = o & 1023;
            b ^= ((b >> 9) & 1) << 5;
            int row = ((s >> 1) << 4) + (b >> 6);
            int k   = ((s & 1) << 5) + ((b & 63) >> 1);
            int gB  = (row * K + k) * 2;
            int gA  = LAYA ? ((row >> 4) * 262144 + (k >> 4) * 512 +
                              (row & 3) * 128 + ((row >> 2) & 3) * 32 + (k & 15) * 2)
                           : gB;
            if (h == 0) { goffA0 = gA; goffB0 = gB; }
            else        { goffA1 = gA; goffB1 = gB; }
        }
    }
    const char* pA0 = A + (LAYA ? (size_t)row0 * 16384 : (size_t)row0 * K * 2);
    const char* pA1 = A + (LAYA ? (size_t)(row0 + 128) * 16384
                                : (size_t)(row0 + 128) * K * 2);
    const char* pB0 = (const char*)B + (size_t)col0 * K * 2;
    const char* pB1 = (const char*)B + (size_t)(col0 + 128) * K * 2;

    // prologue: tile0 [B0,B1,A0,A1] -> E; tile1 [B0,B1,A0] -> O
    STGB(pB0, 32768); STGB(pB1, 49152); STGA(pA0, 0); STGA(pA1, 16384);
    STGB(pB0 + KBB(64), 98304); STGB(pB1 + KBB(64), 114688);
    STGA(pA0 + KAB(64), 65536);
    asm volatile("s_waitcnt vmcnt(6)");   // tile0's 8 loads landed
    BAR();

    f32x4 acc[8][4] = {};
    short8 aP[4], aQ[4], bE[4], bO[4];
    const int NIT = K >> 7;

    for (int it = 0; it < NIT - 1; ++it) {
        const int o0 = it * 128;
        KTILE(ldsB_E, ldsA_E, 1, o0 + 64, 81920,
              1, o0 + 128, 32768, 49152, 0, 2);
        KTILE(ldsB_O, ldsA_O, 1, o0 + 128, 16384,
              1, o0 + 192, 98304, 114688, 65536, 2);
    }
    {
        const int o0 = (NIT - 1) * 128;   // peeled tail
        KTILE(ldsB_E, ldsA_E, 1, o0 + 64, 81920,
              0, 0, 0, 0, 0, 1);          // drain: vmcnt(0)
        KTILE(ldsB_O, ldsA_O, 0, 0, 0,
              0, 0, 0, 0, 0, 0);          // nothing outstanding
    }

    // acc C/D layout (verified m89/m91): col = lane&15, row = (lane>>4)*4 + r
    const float scale = __uint_as_float(*amax) / 6.0f;

    if (RELU_BF16) {
        // H'-blocked store: per (j,i,r) one 2B store, 64 lanes span 128B contiguous
        const int gbit = (lane >> 4) * 32 + (lane & 15) * 2;
        #pragma unroll
        for (int j = 0; j < 4; ++j) {
            const int col = col0 + wn * 64 + j * 16 + (lane & 15);
            const float bvv = bias[col];
            const size_t ktb = (size_t)((col0 >> 4) + wn * 4 + j) * 512;
            #pragma unroll
            for (int i = 0; i < 8; ++i) {
                const size_t rtb = (size_t)(((row0 + wm * 128) >> 4) + i) * 262144;
                #pragma unroll
                for (int r = 0; r < 4; ++r) {
                    float v = fmaxf(acc[i][j][r] * scale + bvv, 0.0f);
                    *(unsigned short*)(outH + rtb + ktb + r * 128 + gbit) = f2bf(v);
                }
            }
        }
    } else {
        // f32 out via LDS: 2 passes (wm groups); 16B-block XOR keyed on (row>>2)&3
        #pragma unroll
        for (int p = 0; p < 2; ++p) {
            if (wm == p) {
                #pragma unroll
                for (int j = 0; j < 4; ++j) {
                    const int colb = wn * 64 + j * 16 + (lane & 15);
                    const float bvv = bias[col0 + colb];
                    #pragma unroll
                    for (int i = 0; i < 8; ++i) {
                        #pragma unroll
                        for (int r = 0; r < 4; ++r) {
                            const int row_l = i * 16 + (lane >> 4) * 4 + r;
                            const int blk = (colb >> 2) ^ (((row_l >> 2) & 3) << 2);
                            *(float*)(lds + row_l * 1024 + blk * 16 + (colb & 3) * 4)
                                = acc[i][j][r] * scale + bvv;
                        }
                    }
                }
            }
            asm volatile("s_waitcnt lgkmcnt(0)");
            BAR();
            #pragma unroll
            for (int q = 0; q < 16; ++q) {
                const int flat  = q * 8192 + tid * 16;
                const int row_l = flat >> 10;
                const int blk0  = (flat >> 4) & 63;
                const int blk   = blk0 ^ (((row_l >> 2) & 3) << 2);
                f32x4 v = *(const f32x4*)(lds + row_l * 1024 + blk * 16);
                *(f32x4*)(outF + (size_t)(row0 + p * 128 + row_l) * N
                                 + col0 + blk0 * 4) = v;
            }
            BAR();
        }
    }
}

extern "C" void kernel_launch(void* const* d_in, const int* in_sizes, int n_in,
                              void* d_out, int out_size, void* d_ws, size_t ws_size,
                              hipStream_t stream) {
    const float* x  = (const float*)d_in[0];   // [8192, 2048]
    const float* W1 = (const float*)d_in[1];   // [8192, 2048]
    const float* b1 = (const float*)d_in[2];   // [8192]
    const float* W2 = (const float*)d_in[3];   // [2048, 8192]
    const float* b2 = (const float*)d_in[4];   // [2048]
    float* out = (float*)d_out;                // [8192, 2048] f32

    const int Bm = 8192, Din = 2048, Dh = 8192, Dout = 2048;
    const size_t nW1 = (size_t)Dh * Din;
    const size_t nW2 = (size_t)Dout * Dh;
    const size_t nX  = (size_t)Bm * Din;
    const size_t nH  = (size_t)Bm * Dh;

    const size_t need = 256 + 2 * (nW1 + nW2 + nX + nH);
    if (ws_size < need) return;

    uint8_t* ws = (uint8_t*)d_ws;
    unsigned int*   amax = (unsigned int*)ws;
    unsigned short* Q1 = (unsigned short*)(ws + 256);
    unsigned short* Q2 = Q1 + nW1;
    unsigned short* Xb = Q2 + nW2;
    char*           H  = (char*)(Xb + nX);     // H'-blocked bf16, nH*2 bytes

    init_amax<<<1, 64, 0, stream>>>(amax);
    absmax_kernel<<<1024, 256, 0, stream>>>((const float4*)W1, nW1 / 4, amax + 0);
    absmax_kernel<<<1024, 256, 0, stream>>>((const float4*)W2, nW2 / 4, amax + 1);
    quant_kernel<<<2048, 256, 0, stream>>>((const float4*)W1, nW1 / 4, amax + 0, (ushort4*)Q1);
    quant_kernel<<<2048, 256, 0, stream>>>((const float4*)W2, nW2 / 4, amax + 1, (ushort4*)Q2);
    cast_bf16_kernel<<<2048, 256, 0, stream>>>((const float4*)x, nX / 4, (ushort4*)Xb);

    // h = relu(scale1 * (x @ Q1^T) + b1) -> H' blocked bf16
    gemm8<1, 0><<<dim3((Dh / 256) * (Bm / 256)), 512, 0, stream>>>(
        (const char*)Xb, Q1, b1, amax + 0, nullptr, H,
        Bm, Dh, Din, /*gx=*/Dh / 256, /*cw=*/16);
    // y = scale2 * (h @ Q2^T) + b2 -> f32 row-major
    gemm8<0, 1><<<dim3((Dout / 256) * (Bm / 256)), 512, 0, stream>>>(
        H, Q2, b2, amax + 1, out, nullptr,
        Bm, Dout, Dh, /*gx=*/Dout / 256, /*cw=*/8);
}